// Round 5
// baseline (128.481 us; speedup 1.0000x reference)
//
#include <hip/hip_runtime.h>
#include <hip/hip_bf16.h>
#include <math.h>

#define BATCH 8
#define SEQ 2048
#define EMBED 1024
#define HEAD 64
#define NROWS (BATCH*SEQ)   // 16384

typedef short bf16x8 __attribute__((ext_vector_type(8)));
typedef short bf16x4 __attribute__((ext_vector_type(4)));
typedef float f32x4  __attribute__((ext_vector_type(4)));

__device__ inline short f2bf(float f) {
    __hip_bfloat16 h = __float2bfloat16(f);
    return *(short*)&h;
}
__device__ inline float bf2f(short s) {
    __hip_bfloat16 h = *(__hip_bfloat16*)&s;
    return __bfloat162float(h);
}

// ---------------------------------------------------------------------------
// Kernel 0: W -> bf16 B-fragment order for 16x16x32 MFMA.
// ---------------------------------------------------------------------------
__global__ __launch_bounds__(256) void prep_w(
    const float* __restrict__ Wq, const float* __restrict__ Wk,
    const float* __restrict__ Wv, short* __restrict__ wt)
{
    int g    = blockIdx.x * 256 + threadIdx.x;   // 24576 total
    int lane = g & 63;
    int frag = g >> 6;           // ct*32 + k32
    int k32  = frag & 31;
    int ct   = frag >> 5;        // 0..11
    int col  = ct * 16 + (lane & 15);
    int mm   = col >> 6, cc = col & 63;
    const float* W = (mm == 0) ? Wq : ((mm == 1) ? Wk : Wv);
    int kb = k32 * 32 + (lane >> 4) * 8;
    bf16x8 o;
#pragma unroll
    for (int j = 0; j < 8; j++)
        o[j] = f2bf(W[(size_t)(kb + j) * HEAD + cc]);
    *(bf16x8*)&wt[(size_t)g * 8] = o;
}

// ---------------------------------------------------------------------------
// Kernel 1: QKV projection (single-stage slab, proven R7). V written
// TRANSPOSED per batch: vt[b][h][t].
// ---------------------------------------------------------------------------
__global__ __launch_bounds__(512, 4) void proj_kernel(
    const float* __restrict__ x, const short* __restrict__ wt,
    short* __restrict__ q, short* __restrict__ k, short* __restrict__ vt)
{
    __shared__ short xs[32][1024];   // 64 KB, XOR-swizzled k8 blocks
    float* psum = (float*)&xs[0][0]; // reuse after compute barrier

    const int tid  = threadIdx.x;
    const int wave = tid >> 6, lane = tid & 63;
    const int m16  = lane & 15, quad = lane >> 4;
    const int cg   = wave & 3;
    const int kh   = wave >> 2;
    const int r0   = blockIdx.x * 32;

    {
        const int row  = tid >> 4;
        const int col4 = tid & 15;
        const float* xr = x + (size_t)(r0 + row) * EMBED;
#pragma unroll
        for (int h = 0; h < 2; h++) {
            float4 f[8];
#pragma unroll
            for (int i = 0; i < 8; i++)
                f[i] = *(const float4*)&xr[(h * 8 + i) * 64 + col4 * 4];
#pragma unroll
            for (int i = 0; i < 8; i++) {
                int c  = (h * 8 + i) * 64 + col4 * 4;
                int k8 = c >> 3, rem = c & 7;
                int cs = ((k8 ^ (row & 7)) << 3) + rem;
                bf16x4 bv;
                bv[0] = f2bf(f[i].x); bv[1] = f2bf(f[i].y);
                bv[2] = f2bf(f[i].z); bv[3] = f2bf(f[i].w);
                *(bf16x4*)&xs[row][cs] = bv;
            }
        }
    }
    __syncthreads();

    f32x4 acc[2][3];
#pragma unroll
    for (int mt = 0; mt < 2; mt++)
#pragma unroll
        for (int j = 0; j < 3; j++) acc[mt][j] = (f32x4){0.f, 0.f, 0.f, 0.f};

#pragma unroll 4
    for (int s = 0; s < 16; s++) {
        int k32  = kh * 16 + s;
        int ksw  = ((k32 * 4 + quad) ^ (m16 & 7)) << 3;
        bf16x8 a0 = *(const bf16x8*)&xs[m16][ksw];
        bf16x8 a1 = *(const bf16x8*)&xs[16 + m16][ksw];
#pragma unroll
        for (int j = 0; j < 3; j++) {
            int ct = cg * 3 + j;
            bf16x8 bb = *(const bf16x8*)&wt[(size_t)((ct * 32 + k32) * 64 + lane) * 8];
            acc[0][j] = __builtin_amdgcn_mfma_f32_16x16x32_bf16(a0, bb, acc[0][j], 0, 0, 0);
            acc[1][j] = __builtin_amdgcn_mfma_f32_16x16x32_bf16(a1, bb, acc[1][j], 0, 0, 0);
        }
    }

    __syncthreads();
    if (kh == 1) {
        float* p = psum + ((size_t)(cg * 64 + lane) * 24);
#pragma unroll
        for (int mt = 0; mt < 2; mt++)
#pragma unroll
            for (int j = 0; j < 3; j++)
                *(f32x4*)&p[(mt * 3 + j) * 4] = acc[mt][j];
    }
    __syncthreads();
    if (kh == 0) {
        const float* p = psum + ((size_t)(cg * 64 + lane) * 24);
        const int bb = r0 >> 11;
        const int tb = r0 & 2047;
#pragma unroll
        for (int mt = 0; mt < 2; mt++)
#pragma unroll
            for (int j = 0; j < 3; j++) {
                f32x4 o = acc[mt][j] + *(const f32x4*)&p[(mt * 3 + j) * 4];
                int gcol = (cg * 3 + j) * 16 + m16;
                int mm = gcol >> 6, cc = gcol & 63;
                if (mm < 2) {
                    short* op = (mm == 0) ? q : k;
#pragma unroll
                    for (int reg = 0; reg < 4; reg++) {
                        int row = r0 + mt * 16 + quad * 4 + reg;
                        op[(size_t)row * HEAD + cc] = f2bf(o[reg]);
                    }
                } else {
                    bf16x4 pk;
                    pk[0] = f2bf(o[0]); pk[1] = f2bf(o[1]);
                    pk[2] = f2bf(o[2]); pk[3] = f2bf(o[3]);
                    int t = tb + mt * 16 + quad * 4;
                    *(bf16x4*)&vt[(((size_t)bb * 64 + cc) << 11) + t] = pk;
                }
            }
    }
}

// ---------------------------------------------------------------------------
// Kernel 2: flash attention with IN-BLOCK 2-way K-split (no split-K blocks,
// no pO/pl, no combine kernel). Grid (qt=32, b=8) = 256 blocks x 512 thr.
// Wave-group g = wave>>2 processes chunks c = 2r+g, r = 0..(qt>>1); both
// groups run lockstep rounds (block-uniform count -> __syncthreads legal);
// each group has private ksh/vsh buffers and fp32 o_acc/lsum. Merge is
// block-local: group 1 parks partials in dead ksh/vsh LDS, one barrier,
// group 0 adds in fp32, scales by 1/(l0+l1), writes out directly.
// R3 lesson honored: zero cross-block communication.
// ---------------------------------------------------------------------------
__global__ __launch_bounds__(512, 2) void attn_kernel(
    const short* __restrict__ qg, const short* __restrict__ kg,
    const short* __restrict__ vtg, float* __restrict__ out)
{
    __shared__ short ksh[2][64][72];   // [grp][t][h]  18432 B
    __shared__ short vsh[2][64][72];   // [grp][h][t]  18432 B
    __shared__ short psh[8][16][72];   // [wave][q=m16][t] 18432 B, wave-private

    const int qt = blockIdx.x;         // 0..31
    const int b  = blockIdx.y;         // 0..7

    const int tid  = threadIdx.x;
    const int wave = tid >> 6, lane = tid & 63;
    const int m16  = lane & 15, quad = lane >> 4;
    const int g    = wave >> 2;        // K-split group (chunk parity)
    const int w4   = wave & 3;         // wave within group -> row block
    const float scale = 0.03125f;      // 1024^-0.5

    const short* qb  = qg  + (size_t)b * SEQ * HEAD;
    const short* kb  = kg  + (size_t)b * SEQ * HEAD;
    const short* vtb = vtg + (size_t)b * HEAD * SEQ;

    const int myrow = qt * 64 + w4 * 16 + m16;     // lane-local q row
    bf16x8 a_q0 = *(const bf16x8*)&qb[(size_t)myrow * HEAD + quad * 8];
    bf16x8 a_q1 = *(const bf16x8*)&qb[(size_t)myrow * HEAD + 32 + quad * 8];

    f32x4 o_acc[4];
#pragma unroll
    for (int i = 0; i < 4; i++) o_acc[i] = (f32x4){0.f, 0.f, 0.f, 0.f};
    float lsum = 0.f;

    // staging: each group's 256 threads stage their own 16 KB chunk
    const int gtid = tid & 255;
    const int srow = gtid >> 3;        // 0..31
    const int sc8  = (gtid & 7) * 8;   // 0..56

    bf16x8 kr0, kr1, vr0, vr1;
    if (g <= qt) {                     // initial chunk c = g
        const int t0 = g * 64;
        kr0 = *(const bf16x8*)&kb[(size_t)(t0 + srow) * HEAD + sc8];
        kr1 = *(const bf16x8*)&kb[(size_t)(t0 + 32 + srow) * HEAD + sc8];
        vr0 = *(const bf16x8*)&vtb[((size_t)srow << 11) + t0 + sc8];
        vr1 = *(const bf16x8*)&vtb[((size_t)(srow + 32) << 11) + t0 + sc8];
    }

    const int R = (qt >> 1) + 1;       // block-uniform round count
    for (int r = 0; r < R; r++) {
        const int c      = 2 * r + g;  // this group's chunk
        const int active = (c <= qt);
        __syncthreads();               // barrier A: prev-round readers done
        if (active) {
            *(bf16x8*)&ksh[g][srow][sc8]      = kr0;
            *(bf16x8*)&ksh[g][srow + 32][sc8] = kr1;
            *(bf16x8*)&vsh[g][srow][sc8]      = vr0;
            *(bf16x8*)&vsh[g][srow + 32][sc8] = vr1;
        }
        __syncthreads();               // barrier B: stores visible
        {
            const int cn = 2 * (r + 1) + g;
            if (cn <= qt) {            // prefetch next round's chunk
                const int tn = cn * 64;
                kr0 = *(const bf16x8*)&kb[(size_t)(tn + srow) * HEAD + sc8];
                kr1 = *(const bf16x8*)&kb[(size_t)(tn + 32 + srow) * HEAD + sc8];
                vr0 = *(const bf16x8*)&vtb[((size_t)srow << 11) + tn + sc8];
                vr1 = *(const bf16x8*)&vtb[((size_t)(srow + 32) << 11) + tn + sc8];
            }
        }
        if (!active) continue;         // wave-uniform; no barrier below

        const int t0 = c * 64;
        // ---- QK^T from LDS, swapped operands: C = S^T, col(lane&15) = q ----
        f32x4 s_t[4];
#pragma unroll
        for (int nt = 0; nt < 4; nt++) {
            bf16x8 ak0 = *(const bf16x8*)&ksh[g][nt * 16 + m16][quad * 8];
            bf16x8 ak1 = *(const bf16x8*)&ksh[g][nt * 16 + m16][32 + quad * 8];
            f32x4 acc = (f32x4){0.f, 0.f, 0.f, 0.f};
            acc = __builtin_amdgcn_mfma_f32_16x16x32_bf16(ak0, a_q0, acc, 0, 0, 0);
            acc = __builtin_amdgcn_mfma_f32_16x16x32_bf16(ak1, a_q1, acc, 0, 0, 0);
            s_t[nt] = acc;
        }

        // ---- no-max softmax; mask only on the diagonal chunk ----
        if (c == qt) {
#pragma unroll
            for (int nt = 0; nt < 4; nt++) {
                bf16x4 pk;
#pragma unroll
                for (int rr = 0; rr < 4; rr++) {
                    int tt = t0 + nt * 16 + quad * 4 + rr;
                    float p = (tt <= myrow) ? __expf(s_t[nt][rr] * scale) : 0.f;
                    lsum += p;
                    pk[rr] = f2bf(p);
                }
                *(bf16x4*)&psh[wave][m16][nt * 16 + quad * 4] = pk;
            }
        } else {
#pragma unroll
            for (int nt = 0; nt < 4; nt++) {
                bf16x4 pk;
#pragma unroll
                for (int rr = 0; rr < 4; rr++) {
                    float p = __expf(s_t[nt][rr] * scale);
                    lsum += p;
                    pk[rr] = f2bf(p);
                }
                *(bf16x4*)&psh[wave][m16][nt * 16 + quad * 4] = pk;
            }
        }
        // psh wave-private: in-wave LDS ordering suffices, no barrier.

        // ---- PV: A-frag natural from psh[q=m16][t]; B-frags from vsh[h][t] ----
#pragma unroll
        for (int ss = 0; ss < 2; ss++) {
            bf16x8 a_p = *(const bf16x8*)&psh[wave][m16][ss * 32 + quad * 8];
#pragma unroll
            for (int ht = 0; ht < 4; ht++) {
                bf16x8 b_v = *(const bf16x8*)&vsh[g][ht * 16 + m16][ss * 32 + quad * 8];
                o_acc[ht] = __builtin_amdgcn_mfma_f32_16x16x32_bf16(a_p, b_v, o_acc[ht], 0, 0, 0);
            }
        }
    }

    // ---- row-sum of l across the 4 quads (every lane gets its row's l) ----
    lsum += __shfl_xor(lsum, 16, 64);
    lsum += __shfl_xor(lsum, 32, 64);

    // ---- block-local merge: group 1 parks partials in dead ksh/vsh LDS ----
    float* osh  = (float*)&ksh[0][0][0];   // [64][65] fp32 = 16640 B < 18432
    float* lshA = (float*)&vsh[0][0][0];   // 64 floats (group 0 l)
    float* lshB = lshA + 64;               // 64 floats (group 1 l)

    __syncthreads();                   // last compute readers done; LDS reuse ok
    if (g == 1) {
#pragma unroll
        for (int ht = 0; ht < 4; ht++)
#pragma unroll
            for (int rr = 0; rr < 4; rr++)
                osh[(w4 * 16 + quad * 4 + rr) * 65 + ht * 16 + m16] = o_acc[ht][rr];
        if (quad == 0) lshB[w4 * 16 + m16] = lsum;
    } else {
        if (quad == 0) lshA[w4 * 16 + m16] = lsum;
    }
    __syncthreads();
    if (g == 0) {
        float* ob = out + ((size_t)b * SEQ + qt * 64) * HEAD;
#pragma unroll
        for (int rr = 0; rr < 4; rr++) {
            const int row = w4 * 16 + quad * 4 + rr;
            const float inv = 1.f / (lshA[row] + lshB[row]);
#pragma unroll
            for (int ht = 0; ht < 4; ht++) {
                float v = (o_acc[ht][rr] + osh[row * 65 + ht * 16 + m16]) * inv;
                ob[(size_t)row * HEAD + ht * 16 + m16] = v;
            }
        }
    }
}

// ---------------------------------------------------------------------------
extern "C" void kernel_launch(void* const* d_in, const int* in_sizes, int n_in,
                              void* d_out, int out_size, void* d_ws, size_t ws_size,
                              hipStream_t stream) {
    const float* x  = (const float*)d_in[0];
    const float* Wq = (const float*)d_in[1];
    const float* Wk = (const float*)d_in[2];
    const float* Wv = (const float*)d_in[3];
    float* out = (float*)d_out;

    short* q  = (short*)d_ws;                       // 1,048,576 elems
    short* k  = q + (size_t)NROWS * HEAD;           // 1,048,576
    short* vt = k + (size_t)NROWS * HEAD;           // 1,048,576 (transposed)
    short* wt = vt + (size_t)NROWS * HEAD;          //   196,608

    prep_w<<<96, 256, 0, stream>>>(Wq, Wk, Wv, wt);
    proj_kernel<<<512, 512, 0, stream>>>(x, wt, q, k, vt);
    attn_kernel<<<dim3(32, 8), 512, 0, stream>>>(q, k, vt, out);
}

// Round 9
// 123.098 us; speedup vs baseline: 1.0437x; 1.0437x over previous
//
#include <hip/hip_runtime.h>
#include <hip/hip_bf16.h>
#include <math.h>

#define BATCH 8
#define SEQ 2048
#define EMBED 1024
#define HEAD 64
#define NROWS (BATCH*SEQ)   // 16384

typedef short bf16x8 __attribute__((ext_vector_type(8)));
typedef short bf16x4 __attribute__((ext_vector_type(4)));
typedef float f32x4  __attribute__((ext_vector_type(4)));

__device__ inline short f2bf(float f) {
    __hip_bfloat16 h = __float2bfloat16(f);
    return *(short*)&h;
}
__device__ inline float bf2f(short s) {
    __hip_bfloat16 h = *(__hip_bfloat16*)&s;
    return __bfloat162float(h);
}

// Dense triangular slots, 64-row qt tiles, 4-chunk segments:
// slots(qt) = (qt>>2)+1; triOff(qt) = 2g(g+1)+(qt&3)(g+1), g=qt>>2. 144/batch.
#define NSLOT 144
__device__ __host__ inline int triOff(int qt) {
    int g = qt >> 2;
    return 2 * g * (g + 1) + (qt & 3) * (g + 1);
}

// ---------------------------------------------------------------------------
// Kernel 0: W -> bf16 B-fragment order for 16x16x32 MFMA.
// ---------------------------------------------------------------------------
__global__ __launch_bounds__(256) void prep_w(
    const float* __restrict__ Wq, const float* __restrict__ Wk,
    const float* __restrict__ Wv, short* __restrict__ wt)
{
    int g    = blockIdx.x * 256 + threadIdx.x;   // 24576 total
    int lane = g & 63;
    int frag = g >> 6;           // ct*32 + k32
    int k32  = frag & 31;
    int ct   = frag >> 5;        // 0..11
    int col  = ct * 16 + (lane & 15);
    int mm   = col >> 6, cc = col & 63;
    const float* W = (mm == 0) ? Wq : ((mm == 1) ? Wk : Wv);
    int kb = k32 * 32 + (lane >> 4) * 8;
    bf16x8 o;
#pragma unroll
    for (int j = 0; j < 8; j++)
        o[j] = f2bf(W[(size_t)(kb + j) * HEAD + cc]);
    *(bf16x8*)&wt[(size_t)g * 8] = o;
}

// ---------------------------------------------------------------------------
// Kernel 1: QKV projection (single-stage slab, proven R7). V written
// TRANSPOSED per batch: vt[b][h][t].
// ---------------------------------------------------------------------------
__global__ __launch_bounds__(512, 4) void proj_kernel(
    const float* __restrict__ x, const short* __restrict__ wt,
    short* __restrict__ q, short* __restrict__ k, short* __restrict__ vt)
{
    __shared__ short xs[32][1024];   // 64 KB, XOR-swizzled k8 blocks
    float* psum = (float*)&xs[0][0]; // reuse after compute barrier

    const int tid  = threadIdx.x;
    const int wave = tid >> 6, lane = tid & 63;
    const int m16  = lane & 15, quad = lane >> 4;
    const int cg   = wave & 3;
    const int kh   = wave >> 2;
    const int r0   = blockIdx.x * 32;

    {
        const int row  = tid >> 4;
        const int col4 = tid & 15;
        const float* xr = x + (size_t)(r0 + row) * EMBED;
#pragma unroll
        for (int h = 0; h < 2; h++) {
            float4 f[8];
#pragma unroll
            for (int i = 0; i < 8; i++)
                f[i] = *(const float4*)&xr[(h * 8 + i) * 64 + col4 * 4];
#pragma unroll
            for (int i = 0; i < 8; i++) {
                int c  = (h * 8 + i) * 64 + col4 * 4;
                int k8 = c >> 3, rem = c & 7;
                int cs = ((k8 ^ (row & 7)) << 3) + rem;
                bf16x4 bv;
                bv[0] = f2bf(f[i].x); bv[1] = f2bf(f[i].y);
                bv[2] = f2bf(f[i].z); bv[3] = f2bf(f[i].w);
                *(bf16x4*)&xs[row][cs] = bv;
            }
        }
    }
    __syncthreads();

    f32x4 acc[2][3];
#pragma unroll
    for (int mt = 0; mt < 2; mt++)
#pragma unroll
        for (int j = 0; j < 3; j++) acc[mt][j] = (f32x4){0.f, 0.f, 0.f, 0.f};

#pragma unroll 4
    for (int s = 0; s < 16; s++) {
        int k32  = kh * 16 + s;
        int ksw  = ((k32 * 4 + quad) ^ (m16 & 7)) << 3;
        bf16x8 a0 = *(const bf16x8*)&xs[m16][ksw];
        bf16x8 a1 = *(const bf16x8*)&xs[16 + m16][ksw];
#pragma unroll
        for (int j = 0; j < 3; j++) {
            int ct = cg * 3 + j;
            bf16x8 bb = *(const bf16x8*)&wt[(size_t)((ct * 32 + k32) * 64 + lane) * 8];
            acc[0][j] = __builtin_amdgcn_mfma_f32_16x16x32_bf16(a0, bb, acc[0][j], 0, 0, 0);
            acc[1][j] = __builtin_amdgcn_mfma_f32_16x16x32_bf16(a1, bb, acc[1][j], 0, 0, 0);
        }
    }

    __syncthreads();
    if (kh == 1) {
        float* p = psum + ((size_t)(cg * 64 + lane) * 24);
#pragma unroll
        for (int mt = 0; mt < 2; mt++)
#pragma unroll
            for (int j = 0; j < 3; j++)
                *(f32x4*)&p[(mt * 3 + j) * 4] = acc[mt][j];
    }
    __syncthreads();
    if (kh == 0) {
        const float* p = psum + ((size_t)(cg * 64 + lane) * 24);
        const int bb = r0 >> 11;
        const int tb = r0 & 2047;
#pragma unroll
        for (int mt = 0; mt < 2; mt++)
#pragma unroll
            for (int j = 0; j < 3; j++) {
                f32x4 o = acc[mt][j] + *(const f32x4*)&p[(mt * 3 + j) * 4];
                int gcol = (cg * 3 + j) * 16 + m16;
                int mm = gcol >> 6, cc = gcol & 63;
                if (mm < 2) {
                    short* op = (mm == 0) ? q : k;
#pragma unroll
                    for (int reg = 0; reg < 4; reg++) {
                        int row = r0 + mt * 16 + quad * 4 + reg;
                        op[(size_t)row * HEAD + cc] = f2bf(o[reg]);
                    }
                } else {
                    bf16x4 pk;
                    pk[0] = f2bf(o[0]); pk[1] = f2bf(o[1]);
                    pk[2] = f2bf(o[2]); pk[3] = f2bf(o[3]);
                    int t = tb + mt * 16 + quad * 4;
                    *(bf16x4*)&vt[(((size_t)bb * 64 + cc) << 11) + t] = pk;
                }
            }
    }
}

// ---------------------------------------------------------------------------
// Kernel 2: split-K flash attention, R2-proven body. XCD-aware 1D grid
// (b = bid&7, slot = bid>>3): consecutive bids round-robin XCDs, so ALL 144
// blocks of batch b land on XCD b -> per-XCD L2 working set drops from
// ~4 MB (all batches, thrash boundary) to ~0.5 MB (one batch's K/V),
// making the ~67 MB of logical K/V re-reads L2-hits.
// Slot densely enumerates active (qt,seg): slot = triOff(qt)+seg; every
// block is active. Body/arithmetic byte-identical to R2.
// ---------------------------------------------------------------------------
__global__ __launch_bounds__(256, 5) void attn_kernel(
    const short* __restrict__ qg, const short* __restrict__ kg,
    const short* __restrict__ vtg,
    short* __restrict__ pO, float* __restrict__ pl)
{
    __shared__ short ksh[64][72];      // [t][h]   9216 B
    __shared__ short vsh[64][72];      // [h][t]   9216 B (from vt, natural)
    __shared__ short psh[4][16][72];   // [wave][q=m16][t] 9216 B, wave-private

    // ---- XCD-pinned decode: b = bid&7 (one batch per XCD), slot = bid>>3 ----
    const int bid  = blockIdx.x;       // 0..1151
    const int b    = bid & 7;
    const int slot = bid >> 3;         // 0..143 = triOff(qt)+seg
    int g = 0;
    while (slot >= 2 * (g + 1) * (g + 2)) g++;          // g = qt>>2, <=7
    const int rem = slot - 2 * g * (g + 1);
    const int qt  = g * 4 + rem / (g + 1);
    const int seg = rem % (g + 1);
    const int c0  = seg * 4;
    const int c1  = min(seg * 4 + 4, qt + 1);           // always c0 < c1

    const int tid  = threadIdx.x;
    const int wave = tid >> 6, lane = tid & 63;
    const int m16  = lane & 15, quad = lane >> 4;
    const float scale = 0.03125f;      // 1024^-0.5

    const short* qb  = qg  + (size_t)b * SEQ * HEAD;
    const short* kb  = kg  + (size_t)b * SEQ * HEAD;
    const short* vtb = vtg + (size_t)b * HEAD * SEQ;

    bf16x8 a_q0, a_q1;
    const int myrow = qt * 64 + wave * 16 + m16;        // lane-local q row
    {
        a_q0 = *(const bf16x8*)&qb[(size_t)myrow * HEAD + quad * 8];
        a_q1 = *(const bf16x8*)&qb[(size_t)myrow * HEAD + 32 + quad * 8];
    }

    f32x4 o_acc[4];
#pragma unroll
    for (int i = 0; i < 4; i++) o_acc[i] = (f32x4){0.f, 0.f, 0.f, 0.f};
    float lsum = 0.f;

    // staging: thread owns two 16B segments of K and two of V (rows r, r+32)
    const int srow = tid >> 3;         // 0..31
    const int sc8  = (tid & 7) * 8;    // 0..56

    bf16x8 kr0 = *(const bf16x8*)&kb[(size_t)(c0 * 64 + srow) * HEAD + sc8];
    bf16x8 kr1 = *(const bf16x8*)&kb[(size_t)(c0 * 64 + 32 + srow) * HEAD + sc8];
    bf16x8 vr0 = *(const bf16x8*)&vtb[((size_t)srow << 11) + c0 * 64 + sc8];
    bf16x8 vr1 = *(const bf16x8*)&vtb[((size_t)(srow + 32) << 11) + c0 * 64 + sc8];

    for (int c = c0; c < c1; c++) {
        const int t0 = c * 64;
        __syncthreads();               // barrier A: prev-iter LDS readers done
        *(bf16x8*)&ksh[srow][sc8]      = kr0;
        *(bf16x8*)&ksh[srow + 32][sc8] = kr1;
        *(bf16x8*)&vsh[srow][sc8]      = vr0;
        *(bf16x8*)&vsh[srow + 32][sc8] = vr1;
        __syncthreads();               // barrier B: stores visible
        if (c + 1 < c1) {              // prefetch next chunk (overlaps compute)
            const int tn = (c + 1) * 64;
            kr0 = *(const bf16x8*)&kb[(size_t)(tn + srow) * HEAD + sc8];
            kr1 = *(const bf16x8*)&kb[(size_t)(tn + 32 + srow) * HEAD + sc8];
            vr0 = *(const bf16x8*)&vtb[((size_t)srow << 11) + tn + sc8];
            vr1 = *(const bf16x8*)&vtb[((size_t)(srow + 32) << 11) + tn + sc8];
        }

        // ---- QK^T from LDS, swapped operands: C = S^T, col(lane&15) = q ----
        f32x4 s_t[4];
#pragma unroll
        for (int nt = 0; nt < 4; nt++) {
            bf16x8 ak0 = *(const bf16x8*)&ksh[nt * 16 + m16][quad * 8];
            bf16x8 ak1 = *(const bf16x8*)&ksh[nt * 16 + m16][32 + quad * 8];
            f32x4 acc = (f32x4){0.f, 0.f, 0.f, 0.f};
            acc = __builtin_amdgcn_mfma_f32_16x16x32_bf16(ak0, a_q0, acc, 0, 0, 0);
            acc = __builtin_amdgcn_mfma_f32_16x16x32_bf16(ak1, a_q1, acc, 0, 0, 0);
            s_t[nt] = acc;
        }

        // ---- no-max softmax; mask only on the diagonal chunk ----
        if (c == qt) {
#pragma unroll
            for (int nt = 0; nt < 4; nt++) {
                bf16x4 pk;
#pragma unroll
                for (int r = 0; r < 4; r++) {
                    int tt = t0 + nt * 16 + quad * 4 + r;
                    float p = (tt <= myrow) ? __expf(s_t[nt][r] * scale) : 0.f;
                    lsum += p;
                    pk[r] = f2bf(p);
                }
                *(bf16x4*)&psh[wave][m16][nt * 16 + quad * 4] = pk;
            }
        } else {
#pragma unroll
            for (int nt = 0; nt < 4; nt++) {
                bf16x4 pk;
#pragma unroll
                for (int r = 0; r < 4; r++) {
                    float p = __expf(s_t[nt][r] * scale);
                    lsum += p;
                    pk[r] = f2bf(p);
                }
                *(bf16x4*)&psh[wave][m16][nt * 16 + quad * 4] = pk;
            }
        }
        // psh wave-private: in-wave LDS ordering suffices, no barrier.

        // ---- PV: A-frag natural from psh[q=m16][t]; B-frags from vsh[h][t] ----
#pragma unroll
        for (int ss = 0; ss < 2; ss++) {
            bf16x8 a_p = *(const bf16x8*)&psh[wave][m16][ss * 32 + quad * 8];
#pragma unroll
            for (int ht = 0; ht < 4; ht++) {
                bf16x8 b_v = *(const bf16x8*)&vsh[ht * 16 + m16][ss * 32 + quad * 8];
                o_acc[ht] = __builtin_amdgcn_mfma_f32_16x16x32_bf16(a_p, b_v, o_acc[ht], 0, 0, 0);
            }
        }
    }

    // ---- epilogue: row-sum of l across the 4 quads, write partials ----
    lsum += __shfl_xor(lsum, 16, 64);
    lsum += __shfl_xor(lsum, 32, 64);
    const size_t pbase = ((size_t)b * NSLOT + slot) * 64;
#pragma unroll
    for (int ht = 0; ht < 4; ht++) {
#pragma unroll
        for (int r = 0; r < 4; r++) {
            int rowt = wave * 16 + quad * 4 + r;
            pO[(pbase + rowt) * 64 + ht * 16 + m16] = f2bf(o_acc[ht][r]);
        }
    }
    if (quad == 0) {
        pl[pbase + wave * 16 + m16] = lsum;
    }
}

// ---------------------------------------------------------------------------
// Kernel 3: combine split-K partials: out = (sum_s O_s) / (sum_s l_s).
// XCD-pinned like attn (b = bid&7): combine for batch b runs on the same
// XCD whose L2 holds attn's just-written pO/pl for that batch -> L2-hot.
// Arithmetic byte-identical to the R2 combine.
// ---------------------------------------------------------------------------
__global__ __launch_bounds__(256) void combine_kernel(
    const short* __restrict__ pO, const float* __restrict__ pl,
    float* __restrict__ out)
{
    const int bid = blockIdx.x;        // 0..511
    const int b   = bid & 7;           // one batch per XCD
    const int gw  = (bid >> 3) * 256 + threadIdx.x;   // 0..16383 within batch
    int h8  = (gw & 7) * 8;
    int row = (gw >> 3) & 2047;
    int qt  = row >> 6, lr = row & 63;
    int ns  = (qt >> 2) + 1;
    size_t base = (size_t)b * NSLOT + triOff(qt);
    float O[8] = {0.f, 0.f, 0.f, 0.f, 0.f, 0.f, 0.f, 0.f};
    float L = 0.f;
    for (int s = 0; s < ns; s++) {
        bf16x8 ov = *(const bf16x8*)&pO[((base + s) * 64 + lr) * 64 + h8];
#pragma unroll
        for (int j = 0; j < 8; j++) O[j] += bf2f(ov[j]);
        L += pl[(base + s) * 64 + lr];
    }
    float inv = 1.f / L;
    float4 o0 = {O[0] * inv, O[1] * inv, O[2] * inv, O[3] * inv};
    float4 o1 = {O[4] * inv, O[5] * inv, O[6] * inv, O[7] * inv};
    size_t obase = ((size_t)b * SEQ + row) * HEAD + h8;
    *(float4*)&out[obase]     = o0;
    *(float4*)&out[obase + 4] = o1;
}

// ---------------------------------------------------------------------------
extern "C" void kernel_launch(void* const* d_in, const int* in_sizes, int n_in,
                              void* d_out, int out_size, void* d_ws, size_t ws_size,
                              hipStream_t stream) {
    const float* x  = (const float*)d_in[0];
    const float* Wq = (const float*)d_in[1];
    const float* Wk = (const float*)d_in[2];
    const float* Wv = (const float*)d_in[3];
    float* out = (float*)d_out;

    short* q  = (short*)d_ws;                       // 1,048,576 elems
    short* k  = q + (size_t)NROWS * HEAD;           // 1,048,576
    short* vt = k + (size_t)NROWS * HEAD;           // 1,048,576 (transposed)
    short* wt = vt + (size_t)NROWS * HEAD;          //   196,608
    short* pO = wt + 196608;                        // 8*144*64*64 = 4,718,592
    float* pl = (float*)(pO + (size_t)BATCH * NSLOT * 64 * 64);  // 73,728 floats

    prep_w<<<96, 256, 0, stream>>>(Wq, Wk, Wv, wt);
    proj_kernel<<<512, 512, 0, stream>>>(x, wt, q, k, vt);
    attn_kernel<<<1152, 256, 0, stream>>>(q, k, vt, pO, pl);
    combine_kernel<<<512, 256, 0, stream>>>(pO, pl, out);
}